// Round 9
// baseline (901.715 us; speedup 1.0000x reference)
//
#include <hip/hip_runtime.h>

typedef float v4f __attribute__((ext_vector_type(4)));

// Problem constants (from reference)
constexpr int CB   = 128;
constexpr int CC   = 12;
constexpr int CL   = 2048;
constexpr int CK   = 8;
constexpr int CG   = 32;
constexpr int CNCP = 6;
constexpr int CND  = 8;
constexpr int ARENA = 3080; // 2048 + 2*512 halo + pad (max over D)

// ---------------------------------------------------------------------------
// Transpose W [pair][g*8+k][9] -> Wt [pair][g][j*8+k] (block-uniform weight
// reads become wide scalar loads).
// ---------------------------------------------------------------------------
__global__ void transposeW(const float* __restrict__ W, float* __restrict__ Wt) {
    int t = blockIdx.x * blockDim.x + threadIdx.x;
    constexpr int total = CND * 2 * CG * CK * 9; // 36864
    if (t >= total) return;
    int j = t % 9; int r = t / 9;
    int k = r % CK; r /= CK;
    int g = r % CG; int pair = r / CG;
    Wt[(pair * CG + g) * 72 + j * 8 + k] =
        W[((pair * (CG * CK)) + g * CK + k) * 9 + j];
}

__device__ __forceinline__ v4f ld4v(const float* p) { return *(const v4f*)p; }

template <typename T>
__device__ __forceinline__ T red64(T v) {
    v += __shfl_xor(v, 32); v += __shfl_xor(v, 16); v += __shfl_xor(v, 8);
    v += __shfl_xor(v, 4);  v += __shfl_xor(v, 2);  v += __shfl_xor(v, 1);
    return v;
}

// 4 contiguous floats at compile-time offset OFF within a v4f-register window.
template <int OFF>
__device__ __forceinline__ v4f pick4(const v4f* w) {
    constexpr int q = OFF >> 2, r = OFF & 3;
    if constexpr (r == 0) return w[q];
    else return __builtin_shufflevector(w[q], w[q + 1], r, r + 1, r + 2, r + 3);
}

// ---------------------------------------------------------------------------
// One WAVE (64-thread block) processes 8 whole groups of one (b, pair):
// stage row -> conv (4 pos/thread, v4f/pk math) -> select/bin in registers ->
// ONE 12-word butterfly per group. MODE: 1 => D=1, 2 => D=2, 0 => generic D.
// ---------------------------------------------------------------------------
template <int MODE>
__device__ void wave_work(const float* __restrict__ X, const float* __restrict__ Wt,
                          const int* __restrict__ I, float* __restrict__ out,
                          float* __restrict__ inp, int b, int pair, int D, int gq)
{
    const int lane  = threadIdx.x;      // 0..63
    const int diffi = pair & 1;
    const int HB    = 4 * D;            // halo width
    const int Lout  = CL - diffi;
    const float* __restrict__ Xb = X + (size_t)b * (CC * CL);

    // zero halos once (row writes never touch them)
    for (int i = lane * 4; i < HB; i += 256) *(v4f*)(inp + i) = (v4f)0.f;
    for (int i = HB + CL + lane * 4; i < ARENA; i += 256) *(v4f*)(inp + i) = (v4f)0.f;

    #pragma unroll 1
    for (int gi = 0; gi < 8; ++gi) {
        const int g = gq * 8 + gi;
        const int* __restrict__ Ig = I + (pair * CG + g) * CNCP;
        const int ch0 = Ig[0], ch1 = Ig[1], ch2 = Ig[2],
                  ch3 = Ig[3], ch4 = Ig[4], ch5 = Ig[5];
        const float *r0 = Xb + ch0 * CL, *r1 = Xb + ch1 * CL, *r2 = Xb + ch2 * CL,
                    *r3 = Xb + ch3 * CL, *r4 = Xb + ch4 * CL, *r5 = Xb + ch5 * CL;

        // ---- stage summed (and optionally diffed) row ----
        #pragma unroll 2
        for (int c = 0; c < 8; ++c) {
            const int pos = c * 256 + lane * 4;
            const v4f s = ld4v(r0 + pos) + ld4v(r1 + pos) + ld4v(r2 + pos)
                        + ld4v(r3 + pos) + ld4v(r4 + pos) + ld4v(r5 + pos);
            if (!diffi) {
                *(v4f*)(inp + HB + pos) = s;
            } else {
                float s4;
                if (pos + 4 < CL)
                    s4 = r0[pos+4] + r1[pos+4] + r2[pos+4]
                       + r3[pos+4] + r4[pos+4] + r5[pos+4];
                else
                    s4 = s[3];     // => diff 0 at padding position 2047
                *(v4f*)(inp + HB + pos) =
                    (v4f){s[1]-s[0], s[2]-s[1], s[3]-s[2], s4-s[3]};
            }
        }
        __syncthreads();  // single-wave barrier: cheap, guarantees LDS order

        const float* __restrict__ Wg = Wt + (pair * CG + g) * 72;

        float bm[8] = {0.f,0.f,0.f,0.f,0.f,0.f,0.f,0.f};
        unsigned p0 = 0, p1 = 0;   // byte-packed min-counts, bins 0-3 / 4-7

        #pragma unroll 1
        for (int p = 0; p < 8; ++p) {
            const int l = p * 256 + lane * 4;   // 4 consecutive positions
            v4f a[8] = {};

            auto dof = [&](v4f t, int j) {
                #pragma unroll
                for (int k = 0; k < 8; ++k)
                    a[k] = __builtin_elementwise_fma(t, (v4f)(Wg[j*8+k]), a[k]);
            };

            if constexpr (MODE == 1) {
                const v4f* wb = (const v4f*)(inp + l);  // HB=4: window base l-4+HB
                v4f w[4] = {wb[0], wb[1], wb[2], wb[3]};
                dof(pick4<0>(w),0); dof(pick4<1>(w),1); dof(pick4<2>(w),2);
                dof(pick4<3>(w),3); dof(pick4<4>(w),4); dof(pick4<5>(w),5);
                dof(pick4<6>(w),6); dof(pick4<7>(w),7); dof(pick4<8>(w),8);
            } else if constexpr (MODE == 2) {
                const v4f* wb = (const v4f*)(inp + l);  // HB=8: window base l-8+HB
                v4f w[5] = {wb[0], wb[1], wb[2], wb[3], wb[4]};
                dof(pick4<0>(w),0);  dof(pick4<2>(w),1);  dof(pick4<4>(w),2);
                dof(pick4<6>(w),3);  dof(pick4<8>(w),4);  dof(pick4<10>(w),5);
                dof(pick4<12>(w),6); dof(pick4<14>(w),7); dof(pick4<16>(w),8);
            } else {
                const float* base = inp + HB + l - 4 * D; // D%4==0 -> aligned b128
                #pragma unroll
                for (int j = 0; j < 9; ++j) dof(ld4v(base + j * D), j);
            }

            const v4f mx = __builtin_elementwise_max(
                __builtin_elementwise_max(__builtin_elementwise_max(a[0],a[1]),
                                          __builtin_elementwise_max(a[2],a[3])),
                __builtin_elementwise_max(__builtin_elementwise_max(a[4],a[5]),
                                          __builtin_elementwise_max(a[6],a[7])));
            const v4f mn = __builtin_elementwise_min(
                __builtin_elementwise_min(__builtin_elementwise_min(a[0],a[1]),
                                          __builtin_elementwise_min(a[2],a[3])),
                __builtin_elementwise_min(__builtin_elementwise_min(a[4],a[5]),
                                          __builtin_elementwise_min(a[6],a[7])));

            #pragma unroll
            for (int pp = 0; pp < 4; ++pp) {
                const float mxs = mx[pp], mns = mn[pp];
                int mi = 7, ni = 7;
                #pragma unroll
                for (int k = 6; k >= 0; --k) {        // descending: first k wins
                    mi = (a[k][pp] == mxs) ? k : mi;
                    ni = (a[k][pp] == mns) ? k : ni;
                }
                const bool valid = (l + pp) < Lout;   // only pos 2047 w/ diff
                const float mg = valid ? mxs : 0.f;
                #pragma unroll
                for (int k = 0; k < 8; ++k) bm[k] += (mi == k) ? mg : 0.f;
                const unsigned inc = valid ? (1u << ((ni & 3) * 8)) : 0u;
                p0 += (ni < 4) ? inc : 0u;
                p1 += (ni >= 4) ? inc : 0u;
            }
        }

        // ---- ONE butterfly per group: 8 floats + 4 u32 (16-bit fields) ----
        unsigned u0 = p0 & 0x00FF00FFu, u1 = (p0 >> 8) & 0x00FF00FFu,
                 u2 = p1 & 0x00FF00FFu, u3 = (p1 >> 8) & 0x00FF00FFu;
        #pragma unroll
        for (int k = 0; k < 8; ++k) bm[k] = red64(bm[k]);
        u0 = red64(u0); u1 = red64(u1); u2 = red64(u2); u3 = red64(u3);

        if (lane == 0) {
            float* o0 = out + (size_t)b * 8192 + (size_t)((pair*2+0)*CG + g) * CK;
            *(v4f*)o0       = (v4f){bm[0], bm[1], bm[2], bm[3]};
            *(v4f*)(o0 + 4) = (v4f){bm[4], bm[5], bm[6], bm[7]};
            float* o1 = out + (size_t)b * 8192 + (size_t)((pair*2+1)*CG + g) * CK;
            *(v4f*)o1       = (v4f){(float)(u0 & 0xFFFFu), (float)(u1 & 0xFFFFu),
                                    (float)(u0 >> 16),     (float)(u1 >> 16)};
            *(v4f*)(o1 + 4) = (v4f){(float)(u2 & 0xFFFFu), (float)(u3 & 0xFFFFu),
                                    (float)(u2 >> 16),     (float)(u3 >> 16)};
        }
        __syncthreads();  // conv reads done before next group's stage writes
    }
}

__global__ void __launch_bounds__(64, 3)
hydra(const float* __restrict__ X, const float* __restrict__ Wt,
      const int* __restrict__ I, float* __restrict__ out)
{
    __shared__ float inp[ARENA];  // 12.32 KB -> 12 waves/CU (LDS-limited)
    const int blk = blockIdx.x;
    // XCD swizzle (proven in R8: FETCH 496 GB -> 7 MB): 16 batches per XCD.
    const int x  = blk & 7;
    const int r  = blk >> 3;              // [0,1024)
    const int b  = x * 16 + (r >> 6);
    const int pair = r & 15;
    const int gq = (r >> 4) & 3;
    const int di = pair >> 1;
    if (di == 0)      wave_work<1>(X, Wt, I, out, inp, b, pair, 1, gq);
    else if (di == 1) wave_work<2>(X, Wt, I, out, inp, b, pair, 2, gq);
    else              wave_work<0>(X, Wt, I, out, inp, b, pair, 1 << di, gq);
}

extern "C" void kernel_launch(void* const* d_in, const int* in_sizes, int n_in,
                              void* d_out, int out_size, void* d_ws, size_t ws_size,
                              hipStream_t stream)
{
    const float* X = (const float*)d_in[0];
    const float* W = (const float*)d_in[1];
    const int*   I = (const int*)d_in[2];
    float* out = (float*)d_out;
    float* Wt  = (float*)d_ws; // 36864 floats = 144 KiB scratch

    transposeW<<<dim3((36864 + 255) / 256), dim3(256), 0, stream>>>(W, Wt);
    // 128 b x 16 pair x 4 gq = 8192 one-wave blocks
    hydra<<<dim3(8192), dim3(64), 0, stream>>>(X, Wt, I, out);
}

// Round 10
// 565.340 us; speedup vs baseline: 1.5950x; 1.5950x over previous
//
#include <hip/hip_runtime.h>

typedef float v2f __attribute__((ext_vector_type(2)));

// Problem constants (from reference)
constexpr int CB   = 128;
constexpr int CC   = 12;
constexpr int CL   = 2048;
constexpr int CK   = 8;
constexpr int CG   = 32;
constexpr int CNCP = 6;
constexpr int CND  = 8;
constexpr int HALO = 512;   // max tap reach = 4*128
constexpr int BUF  = HALO + CL + HALO + 16;

// ---------------------------------------------------------------------------
// Transpose W [pair][g*8+k][9] -> Wt [pair][g][j*8+k].
// ---------------------------------------------------------------------------
__global__ void transposeW(const float* __restrict__ W, float* __restrict__ Wt) {
    int t = blockIdx.x * blockDim.x + threadIdx.x;
    constexpr int total = CND * 2 * CG * CK * 9; // 36864
    if (t >= total) return;
    int j = t % 9; int r = t / 9;
    int k = r % CK; r /= CK;
    int g = r % CG; int pair = r / CG;
    Wt[(pair * CG + g) * 72 + j * 8 + k] =
        W[((pair * (CG * CK)) + g * CK + k) * 9 + j];
}

__device__ __forceinline__ float4 ld4(const float* p) { return *(const float4*)p; }
__device__ __forceinline__ v2f vmax(v2f a, v2f b) { return __builtin_elementwise_max(a, b); }
__device__ __forceinline__ v2f vmin(v2f a, v2f b) { return __builtin_elementwise_min(a, b); }

// ---------------------------------------------------------------------------
// R8 champion structure; only the per-group reduction changed: reduce-scatter
// (10 shuffles per 8-bin set) instead of 16 full butterflies (96 shuffles).
// ---------------------------------------------------------------------------
__global__ void __launch_bounds__(256)
hydra_fused(const float* __restrict__ X, const float* __restrict__ Wt,
            const int* __restrict__ I, float* __restrict__ out)
{
    __shared__ float inp[BUF];
    __shared__ float wavehist[4 * 16];
    const int tid = threadIdx.x;
    // XCD swizzle (R8-proven: FETCH 496 GB -> 7 MB)
    const int blk  = blockIdx.x;
    const int x    = blk & 7;
    const int r    = blk >> 3;
    const int b    = x * 16 + (r >> 4);
    const int pair = r & 15;
    const int di    = pair >> 1;
    const int diffi = pair & 1;
    const int D     = 1 << di;
    const int Lout  = CL - diffi;
    const float* __restrict__ Xb = X + (size_t)b * (CC * CL);

    for (int i = tid; i < HALO; i += 256) inp[i] = 0.f;
    for (int i = HALO + CL + tid; i < BUF; i += 256) inp[i] = 0.f;

    #pragma unroll 1
    for (int g = 0; g < CG; ++g) {
        // ---- stage summed (and optionally diffed) row for this group ----
        const int* __restrict__ Ig = I + (pair * CG + g) * CNCP;
        const int ch0 = Ig[0], ch1 = Ig[1], ch2 = Ig[2],
                  ch3 = Ig[3], ch4 = Ig[4], ch5 = Ig[5];
        const float* r0 = Xb + ch0 * CL; const float* r1 = Xb + ch1 * CL;
        const float* r2 = Xb + ch2 * CL; const float* r3 = Xb + ch3 * CL;
        const float* r4 = Xb + ch4 * CL; const float* r5 = Xb + ch5 * CL;

        #pragma unroll
        for (int cc = 0; cc < 2; ++cc) {
            const int pos = cc * 1024 + tid * 4;
            const float4 x0 = ld4(r0 + pos), x1 = ld4(r1 + pos), x2 = ld4(r2 + pos),
                         x3 = ld4(r3 + pos), x4 = ld4(r4 + pos), x5 = ld4(r5 + pos);
            float4 s;
            s.x = ((x0.x + x1.x) + (x2.x + x3.x)) + (x4.x + x5.x);
            s.y = ((x0.y + x1.y) + (x2.y + x3.y)) + (x4.y + x5.y);
            s.z = ((x0.z + x1.z) + (x2.z + x3.z)) + (x4.z + x5.z);
            s.w = ((x0.w + x1.w) + (x2.w + x3.w)) + (x4.w + x5.w);
            if (!diffi) {
                *(float4*)&inp[HALO + pos] = s;
            } else {
                float s4;
                if (pos + 4 < CL)
                    s4 = ((r0[pos + 4] + r1[pos + 4]) + (r2[pos + 4] + r3[pos + 4]))
                         + (r4[pos + 4] + r5[pos + 4]);
                else
                    s4 = s.w; // => diff 0 at padding position 2047
                const float4 d = make_float4(s.y - s.x, s.z - s.y, s.w - s.z, s4 - s.w);
                *(float4*)&inp[HALO + pos] = d;
            }
        }
        __syncthreads();

        // ---- conv + select + register bins, 2 positions/thread (packed) ----
        const float* __restrict__ Wg = Wt + (pair * CG + g) * 72;
        v2f bm0 = {0,0}, bm1 = {0,0}, bm2 = {0,0}, bm3 = {0,0},
            bm4 = {0,0}, bm5 = {0,0}, bm6 = {0,0}, bm7 = {0,0};
        unsigned bnpack = 0; // 8 nibble counters, <=8 each per g per thread

        #pragma unroll 1
        for (int p = 0; p < 4; ++p) {
            const int l = p * 512 + tid * 2;          // even; positions l, l+1
            v2f a0 = {0,0}, a1 = {0,0}, a2 = {0,0}, a3 = {0,0},
                a4 = {0,0}, a5 = {0,0}, a6 = {0,0}, a7 = {0,0};

            #define FK2(J, TV) { const float* wj = Wg + (J) * 8; \
                a0 = __builtin_elementwise_fma((v2f){wj[0], wj[0]}, TV, a0); \
                a1 = __builtin_elementwise_fma((v2f){wj[1], wj[1]}, TV, a1); \
                a2 = __builtin_elementwise_fma((v2f){wj[2], wj[2]}, TV, a2); \
                a3 = __builtin_elementwise_fma((v2f){wj[3], wj[3]}, TV, a3); \
                a4 = __builtin_elementwise_fma((v2f){wj[4], wj[4]}, TV, a4); \
                a5 = __builtin_elementwise_fma((v2f){wj[5], wj[5]}, TV, a5); \
                a6 = __builtin_elementwise_fma((v2f){wj[6], wj[6]}, TV, a6); \
                a7 = __builtin_elementwise_fma((v2f){wj[7], wj[7]}, TV, a7); }

            if (di == 0) {
                const float* base = &inp[HALO + l - 4];
                const v2f W0 = *(const v2f*)(base + 0), W1 = *(const v2f*)(base + 2),
                          W2 = *(const v2f*)(base + 4), W3 = *(const v2f*)(base + 6),
                          W4 = *(const v2f*)(base + 8);
                FK2(0, W0)
                FK2(1, ((v2f){W0.y, W1.x}))
                FK2(2, W1)
                FK2(3, ((v2f){W1.y, W2.x}))
                FK2(4, W2)
                FK2(5, ((v2f){W2.y, W3.x}))
                FK2(6, W3)
                FK2(7, ((v2f){W3.y, W4.x}))
                FK2(8, W4)
            } else {
                const float* base = &inp[HALO + l - 4 * D];
                #pragma unroll
                for (int j = 0; j < 9; ++j) {
                    const v2f tv = *(const v2f*)(base + j * D);
                    FK2(j, tv)
                }
            }
            #undef FK2

            const v2f mx2 = vmax(vmax(vmax(a0, a1), vmax(a2, a3)),
                                 vmax(vmax(a4, a5), vmax(a6, a7)));
            const v2f mn2 = vmin(vmin(vmin(a0, a1), vmin(a2, a3)),
                                 vmin(vmin(a4, a5), vmin(a6, a7)));

            int mi0 = 7, mi1 = 7, ni0 = 7, ni1 = 7;
            #define SCANK(K, ak) \
                mi0 = (ak.x == mx2.x) ? (K) : mi0; mi1 = (ak.y == mx2.y) ? (K) : mi1; \
                ni0 = (ak.x == mn2.x) ? (K) : ni0; ni1 = (ak.y == mn2.y) ? (K) : ni1;
            SCANK(6, a6) SCANK(5, a5) SCANK(4, a4) SCANK(3, a3)
            SCANK(2, a2) SCANK(1, a1) SCANK(0, a0)
            #undef SCANK

            const bool v1ok = (l + 1) < Lout;
            if (!v1ok) mi1 = 8;

            #define BINK(K) bm##K += (v2f){ (mi0 == (K)) ? mx2.x : 0.f, \
                                            (mi1 == (K)) ? mx2.y : 0.f };
            BINK(0) BINK(1) BINK(2) BINK(3) BINK(4) BINK(5) BINK(6) BINK(7)
            #undef BINK
            bnpack += (1u << (ni0 * 4)) + (v1ok ? (1u << (ni1 * 4)) : 0u);
        }

        // ---- fold parities, unpack nibbles ----
        float f0 = bm0.x + bm0.y, f1 = bm1.x + bm1.y, f2 = bm2.x + bm2.y,
              f3 = bm3.x + bm3.y, f4 = bm4.x + bm4.y, f5 = bm5.x + bm5.y,
              f6 = bm6.x + bm6.y, f7 = bm7.x + bm7.y;
        float h0 = (float)((bnpack >>  0) & 15), h1 = (float)((bnpack >>  4) & 15),
              h2 = (float)((bnpack >>  8) & 15), h3 = (float)((bnpack >> 12) & 15),
              h4 = (float)((bnpack >> 16) & 15), h5 = (float)((bnpack >> 20) & 15),
              h6 = (float)((bnpack >> 24) & 15), h7 = (float)((bnpack >> 28) & 15);

        // ---- reduce-scatter over 64 lanes: payload 8->4->2->1, then 3
        //      copy-combine steps. 10 shuffles per 8-bin set (was 48). ----
        const int lane = tid & 63;
        const bool l5 = (lane & 32) != 0, l4 = (lane & 16) != 0, l3 = (lane & 8) != 0;

        #define RSCAT(q, v0, v1, v2, v3, v4, v5, v6, v7)                          \
            float q;                                                              \
            {                                                                     \
                float k0 = l5 ? v4 : v0, s0 = l5 ? v0 : v4;                       \
                float k1 = l5 ? v5 : v1, s1 = l5 ? v1 : v5;                       \
                float k2 = l5 ? v6 : v2, s2 = l5 ? v2 : v6;                       \
                float k3 = l5 ? v7 : v3, s3 = l5 ? v3 : v7;                       \
                k0 += __shfl_xor(s0, 32); k1 += __shfl_xor(s1, 32);               \
                k2 += __shfl_xor(s2, 32); k3 += __shfl_xor(s3, 32);               \
                float m0 = l4 ? k2 : k0, t0 = l4 ? k0 : k2;                       \
                float m1 = l4 ? k3 : k1, t1 = l4 ? k1 : k3;                       \
                m0 += __shfl_xor(t0, 16); m1 += __shfl_xor(t1, 16);               \
                q = l3 ? m1 : m0; float u = l3 ? m0 : m1;                         \
                q += __shfl_xor(u, 8);                                            \
                q += __shfl_xor(q, 4); q += __shfl_xor(q, 2);                     \
                q += __shfl_xor(q, 1);                                            \
            }
        RSCAT(qf, f0, f1, f2, f3, f4, f5, f6, f7)
        RSCAT(qc, h0, h1, h2, h3, h4, h5, h6, h7)
        #undef RSCAT

        // lane holds totals for bin = 4*bit5 + 2*bit4 + bit3
        if ((lane & 7) == 0) {
            const int bin = (l5 ? 4 : 0) + (l4 ? 2 : 0) + (l3 ? 1 : 0);
            float* wh = wavehist + (tid >> 6) * 16;
            wh[bin]     = qf;
            wh[8 + bin] = qc;
        }
        __syncthreads();

        if (tid < 16) {
            const float s = wavehist[tid] + wavehist[16 + tid]
                          + wavehist[32 + tid] + wavehist[48 + tid];
            const int which = tid >> 3, k = tid & 7;
            out[(size_t)b * 8192 + ((pair * 2 + which) * CG + g) * CK + k] = s;
        }
    }
}

extern "C" void kernel_launch(void* const* d_in, const int* in_sizes, int n_in,
                              void* d_out, int out_size, void* d_ws, size_t ws_size,
                              hipStream_t stream)
{
    const float* X = (const float*)d_in[0];
    const float* W = (const float*)d_in[1];
    const int*   I = (const int*)d_in[2];
    float* out = (float*)d_out;
    float* Wt  = (float*)d_ws; // 36864 floats = 144 KiB scratch

    transposeW<<<dim3((36864 + 255) / 256), dim3(256), 0, stream>>>(W, Wt);
    hydra_fused<<<dim3(CB * 16), dim3(256), 0, stream>>>(X, Wt, I, out);
}

// Round 11
// 559.775 us; speedup vs baseline: 1.6109x; 1.0099x over previous
//
#include <hip/hip_runtime.h>

typedef float    v2f __attribute__((ext_vector_type(2)));
typedef unsigned v2u __attribute__((ext_vector_type(2)));

// Problem constants (from reference)
constexpr int CB   = 128;
constexpr int CC   = 12;
constexpr int CL   = 2048;
constexpr int CK   = 8;
constexpr int CG   = 32;
constexpr int CNCP = 6;
constexpr int CND  = 8;
constexpr int HALO = 512;   // max tap reach = 4*128
constexpr int BUF  = HALO + CL + HALO + 16;

// ---------------------------------------------------------------------------
// Transpose W [pair][g*8+k][9] -> Wt [pair][g][j*8+k].
// ---------------------------------------------------------------------------
__global__ void transposeW(const float* __restrict__ W, float* __restrict__ Wt) {
    int t = blockIdx.x * blockDim.x + threadIdx.x;
    constexpr int total = CND * 2 * CG * CK * 9; // 36864
    if (t >= total) return;
    int j = t % 9; int r = t / 9;
    int k = r % CK; r /= CK;
    int g = r % CG; int pair = r / CG;
    Wt[(pair * CG + g) * 72 + j * 8 + k] =
        W[((pair * (CG * CK)) + g * CK + k) * 9 + j];
}

__device__ __forceinline__ float4 ld4(const float* p) { return *(const float4*)p; }
__device__ __forceinline__ v2f vmax(v2f a, v2f b) { return __builtin_elementwise_max(a, b); }
__device__ __forceinline__ v2f vmin(v2f a, v2f b) { return __builtin_elementwise_min(a, b); }

// Embed kernel index k in the 3 low mantissa bits: (bits & ~7) | k.
// One v_and_or_b32 per 32-bit half. Max/min trees then carry argmax/argmin
// in the low bits; value perturbation <= 2^-20 relative (threshold 33.76).
__device__ __forceinline__ v2f packidx(v2f a, unsigned code) {
    v2u u = __builtin_bit_cast(v2u, a);
    u = (u & 0xFFFFFFF8u) | code;
    return __builtin_bit_cast(v2f, u);
}
__device__ __forceinline__ int lowbits(float v) {
    return (int)(__builtin_bit_cast(unsigned, v) & 7u);
}

// ---------------------------------------------------------------------------
// R10 champion structure; select path replaced by index-in-mantissa packing
// (single pk_max/pk_min trees give value AND index; 56-instr scans deleted).
// ---------------------------------------------------------------------------
__global__ void __launch_bounds__(256)
hydra_fused(const float* __restrict__ X, const float* __restrict__ Wt,
            const int* __restrict__ I, float* __restrict__ out)
{
    __shared__ float inp[BUF];
    __shared__ float wavehist[4 * 16];
    const int tid = threadIdx.x;
    // XCD swizzle (R8-proven: FETCH 496 GB -> 7 MB)
    const int blk  = blockIdx.x;
    const int x    = blk & 7;
    const int r    = blk >> 3;
    const int b    = x * 16 + (r >> 4);
    const int pair = r & 15;
    const int di    = pair >> 1;
    const int diffi = pair & 1;
    const int D     = 1 << di;
    const int Lout  = CL - diffi;
    const float* __restrict__ Xb = X + (size_t)b * (CC * CL);

    for (int i = tid; i < HALO; i += 256) inp[i] = 0.f;
    for (int i = HALO + CL + tid; i < BUF; i += 256) inp[i] = 0.f;

    #pragma unroll 1
    for (int g = 0; g < CG; ++g) {
        // ---- stage summed (and optionally diffed) row for this group ----
        const int* __restrict__ Ig = I + (pair * CG + g) * CNCP;
        const int ch0 = Ig[0], ch1 = Ig[1], ch2 = Ig[2],
                  ch3 = Ig[3], ch4 = Ig[4], ch5 = Ig[5];
        const float* r0 = Xb + ch0 * CL; const float* r1 = Xb + ch1 * CL;
        const float* r2 = Xb + ch2 * CL; const float* r3 = Xb + ch3 * CL;
        const float* r4 = Xb + ch4 * CL; const float* r5 = Xb + ch5 * CL;

        #pragma unroll
        for (int cc = 0; cc < 2; ++cc) {
            const int pos = cc * 1024 + tid * 4;
            const float4 x0 = ld4(r0 + pos), x1 = ld4(r1 + pos), x2 = ld4(r2 + pos),
                         x3 = ld4(r3 + pos), x4 = ld4(r4 + pos), x5 = ld4(r5 + pos);
            float4 s;
            s.x = ((x0.x + x1.x) + (x2.x + x3.x)) + (x4.x + x5.x);
            s.y = ((x0.y + x1.y) + (x2.y + x3.y)) + (x4.y + x5.y);
            s.z = ((x0.z + x1.z) + (x2.z + x3.z)) + (x4.z + x5.z);
            s.w = ((x0.w + x1.w) + (x2.w + x3.w)) + (x4.w + x5.w);
            if (!diffi) {
                *(float4*)&inp[HALO + pos] = s;
            } else {
                float s4;
                if (pos + 4 < CL)
                    s4 = ((r0[pos + 4] + r1[pos + 4]) + (r2[pos + 4] + r3[pos + 4]))
                         + (r4[pos + 4] + r5[pos + 4]);
                else
                    s4 = s.w; // => diff 0 at padding position 2047
                const float4 d = make_float4(s.y - s.x, s.z - s.y, s.w - s.z, s4 - s.w);
                *(float4*)&inp[HALO + pos] = d;
            }
        }
        __syncthreads();

        // ---- conv + packed-index select + register bins, 2 pos/thread ----
        const float* __restrict__ Wg = Wt + (pair * CG + g) * 72;
        v2f bm0 = {0,0}, bm1 = {0,0}, bm2 = {0,0}, bm3 = {0,0},
            bm4 = {0,0}, bm5 = {0,0}, bm6 = {0,0}, bm7 = {0,0};
        unsigned bnpack = 0; // 8 nibble counters, <=8 each per g per thread

        #pragma unroll 1
        for (int p = 0; p < 4; ++p) {
            const int l = p * 512 + tid * 2;          // even; positions l, l+1
            v2f a0 = {0,0}, a1 = {0,0}, a2 = {0,0}, a3 = {0,0},
                a4 = {0,0}, a5 = {0,0}, a6 = {0,0}, a7 = {0,0};

            #define FK2(J, TV) { const float* wj = Wg + (J) * 8; \
                a0 = __builtin_elementwise_fma((v2f){wj[0], wj[0]}, TV, a0); \
                a1 = __builtin_elementwise_fma((v2f){wj[1], wj[1]}, TV, a1); \
                a2 = __builtin_elementwise_fma((v2f){wj[2], wj[2]}, TV, a2); \
                a3 = __builtin_elementwise_fma((v2f){wj[3], wj[3]}, TV, a3); \
                a4 = __builtin_elementwise_fma((v2f){wj[4], wj[4]}, TV, a4); \
                a5 = __builtin_elementwise_fma((v2f){wj[5], wj[5]}, TV, a5); \
                a6 = __builtin_elementwise_fma((v2f){wj[6], wj[6]}, TV, a6); \
                a7 = __builtin_elementwise_fma((v2f){wj[7], wj[7]}, TV, a7); }

            if (di == 0) {
                const float* base = &inp[HALO + l - 4];
                const v2f W0 = *(const v2f*)(base + 0), W1 = *(const v2f*)(base + 2),
                          W2 = *(const v2f*)(base + 4), W3 = *(const v2f*)(base + 6),
                          W4 = *(const v2f*)(base + 8);
                FK2(0, W0)
                FK2(1, ((v2f){W0.y, W1.x}))
                FK2(2, W1)
                FK2(3, ((v2f){W1.y, W2.x}))
                FK2(4, W2)
                FK2(5, ((v2f){W2.y, W3.x}))
                FK2(6, W3)
                FK2(7, ((v2f){W3.y, W4.x}))
                FK2(8, W4)
            } else {
                const float* base = &inp[HALO + l - 4 * D];
                #pragma unroll
                for (int j = 0; j < 9; ++j) {
                    const v2f tv = *(const v2f*)(base + j * D);
                    FK2(j, tv)
                }
            }
            #undef FK2

            // pack index into low mantissa bits, then single max/min trees
            const v2f q0 = packidx(a0, 0), q1 = packidx(a1, 1),
                      q2 = packidx(a2, 2), q3 = packidx(a3, 3),
                      q4 = packidx(a4, 4), q5 = packidx(a5, 5),
                      q6 = packidx(a6, 6), q7 = packidx(a7, 7);
            const v2f mx2 = vmax(vmax(vmax(q0, q1), vmax(q2, q3)),
                                 vmax(vmax(q4, q5), vmax(q6, q7)));
            const v2f mn2 = vmin(vmin(vmin(q0, q1), vmin(q2, q3)),
                                 vmin(vmin(q4, q5), vmin(q6, q7)));

            int mi0 = lowbits(mx2.x), mi1 = lowbits(mx2.y);
            const int ni0 = lowbits(mn2.x), ni1 = lowbits(mn2.y);

            const bool v1ok = (l + 1) < Lout;
            if (!v1ok) mi1 = 8;

            #define BINK(K) bm##K += (v2f){ (mi0 == (K)) ? mx2.x : 0.f, \
                                            (mi1 == (K)) ? mx2.y : 0.f };
            BINK(0) BINK(1) BINK(2) BINK(3) BINK(4) BINK(5) BINK(6) BINK(7)
            #undef BINK
            bnpack += (1u << (ni0 * 4)) + (v1ok ? (1u << (ni1 * 4)) : 0u);
        }

        // ---- fold parities, unpack nibbles ----
        float f0 = bm0.x + bm0.y, f1 = bm1.x + bm1.y, f2 = bm2.x + bm2.y,
              f3 = bm3.x + bm3.y, f4 = bm4.x + bm4.y, f5 = bm5.x + bm5.y,
              f6 = bm6.x + bm6.y, f7 = bm7.x + bm7.y;
        float h0 = (float)((bnpack >>  0) & 15), h1 = (float)((bnpack >>  4) & 15),
              h2 = (float)((bnpack >>  8) & 15), h3 = (float)((bnpack >> 12) & 15),
              h4 = (float)((bnpack >> 16) & 15), h5 = (float)((bnpack >> 20) & 15),
              h6 = (float)((bnpack >> 24) & 15), h7 = (float)((bnpack >> 28) & 15);

        // ---- reduce-scatter over 64 lanes (R10-proven, 10 shuffles/set) ----
        const int lane = tid & 63;
        const bool l5 = (lane & 32) != 0, l4 = (lane & 16) != 0, l3 = (lane & 8) != 0;

        #define RSCAT(q, v0, v1, v2, v3, v4, v5, v6, v7)                          \
            float q;                                                              \
            {                                                                     \
                float k0 = l5 ? v4 : v0, s0 = l5 ? v0 : v4;                       \
                float k1 = l5 ? v5 : v1, s1 = l5 ? v1 : v5;                       \
                float k2 = l5 ? v6 : v2, s2 = l5 ? v2 : v6;                       \
                float k3 = l5 ? v7 : v3, s3 = l5 ? v3 : v7;                       \
                k0 += __shfl_xor(s0, 32); k1 += __shfl_xor(s1, 32);               \
                k2 += __shfl_xor(s2, 32); k3 += __shfl_xor(s3, 32);               \
                float m0 = l4 ? k2 : k0, t0 = l4 ? k0 : k2;                       \
                float m1 = l4 ? k3 : k1, t1 = l4 ? k1 : k3;                       \
                m0 += __shfl_xor(t0, 16); m1 += __shfl_xor(t1, 16);               \
                q = l3 ? m1 : m0; float u = l3 ? m0 : m1;                         \
                q += __shfl_xor(u, 8);                                            \
                q += __shfl_xor(q, 4); q += __shfl_xor(q, 2);                     \
                q += __shfl_xor(q, 1);                                            \
            }
        RSCAT(qf, f0, f1, f2, f3, f4, f5, f6, f7)
        RSCAT(qc, h0, h1, h2, h3, h4, h5, h6, h7)
        #undef RSCAT

        // lane holds totals for bin = 4*bit5 + 2*bit4 + bit3
        if ((lane & 7) == 0) {
            const int bin = (l5 ? 4 : 0) + (l4 ? 2 : 0) + (l3 ? 1 : 0);
            float* wh = wavehist + (tid >> 6) * 16;
            wh[bin]     = qf;
            wh[8 + bin] = qc;
        }
        __syncthreads();

        if (tid < 16) {
            const float s = wavehist[tid] + wavehist[16 + tid]
                          + wavehist[32 + tid] + wavehist[48 + tid];
            const int which = tid >> 3, k = tid & 7;
            out[(size_t)b * 8192 + ((pair * 2 + which) * CG + g) * CK + k] = s;
        }
    }
}

extern "C" void kernel_launch(void* const* d_in, const int* in_sizes, int n_in,
                              void* d_out, int out_size, void* d_ws, size_t ws_size,
                              hipStream_t stream)
{
    const float* X = (const float*)d_in[0];
    const float* W = (const float*)d_in[1];
    const int*   I = (const int*)d_in[2];
    float* out = (float*)d_out;
    float* Wt  = (float*)d_ws; // 36864 floats = 144 KiB scratch

    transposeW<<<dim3((36864 + 255) / 256), dim3(256), 0, stream>>>(W, Wt);
    hydra_fused<<<dim3(CB * 16), dim3(256), 0, stream>>>(X, Wt, I, out);
}

// Round 12
// 475.934 us; speedup vs baseline: 1.8946x; 1.1762x over previous
//
#include <hip/hip_runtime.h>

typedef float    v2f __attribute__((ext_vector_type(2)));
typedef unsigned v2u __attribute__((ext_vector_type(2)));

// Problem constants (from reference)
constexpr int CB   = 128;
constexpr int CC   = 12;
constexpr int CL   = 2048;
constexpr int CK   = 8;
constexpr int CG   = 32;
constexpr int CNCP = 6;
constexpr int CND  = 8;
constexpr int HALO = 512;   // max tap reach = 4*128
constexpr int BUF  = HALO + CL + HALO + 16;

// ---------------------------------------------------------------------------
// Transpose W [pair][g*8+k][9] -> Wt [pair][g][j*8+k].
// ---------------------------------------------------------------------------
__global__ void transposeW(const float* __restrict__ W, float* __restrict__ Wt) {
    int t = blockIdx.x * blockDim.x + threadIdx.x;
    constexpr int total = CND * 2 * CG * CK * 9; // 36864
    if (t >= total) return;
    int j = t % 9; int r = t / 9;
    int k = r % CK; r /= CK;
    int g = r % CG; int pair = r / CG;
    Wt[(pair * CG + g) * 72 + j * 8 + k] =
        W[((pair * (CG * CK)) + g * CK + k) * 9 + j];
}

__device__ __forceinline__ float4 ld4(const float* p) { return *(const float4*)p; }
__device__ __forceinline__ v2f vmax(v2f a, v2f b) { return __builtin_elementwise_max(a, b); }
__device__ __forceinline__ v2f vmin(v2f a, v2f b) { return __builtin_elementwise_min(a, b); }

// Embed kernel index k in the 3 low mantissa bits (R11-proven).
__device__ __forceinline__ v2f packidx(v2f a, unsigned code) {
    v2u u = __builtin_bit_cast(v2u, a);
    u = (u & 0xFFFFFFF8u) | code;
    return __builtin_bit_cast(v2f, u);
}
__device__ __forceinline__ int lowbits(float v) {
    return (int)(__builtin_bit_cast(unsigned, v) & 7u);
}

// ---------------------------------------------------------------------------
// R11 structure, but block = (b, pair, gq): 8 groups per block, 8192 blocks
// -> 4+ scheduling generations with backfill (R11 was a single generation of
// exactly 8 blocks/CU: heterogeneous block costs -> 48% achieved occupancy).
// ---------------------------------------------------------------------------
__global__ void __launch_bounds__(256)
hydra_fused(const float* __restrict__ X, const float* __restrict__ Wt,
            const int* __restrict__ I, float* __restrict__ out)
{
    __shared__ float inp[BUF];
    __shared__ float wavehist[4 * 16];
    const int tid = threadIdx.x;
    // XCD swizzle (R8-proven): 16 batches per XCD; pair varies fastest so
    // backfill queues mix cheap/expensive blocks.
    const int blk  = blockIdx.x;
    const int x    = blk & 7;
    const int r    = blk >> 3;            // [0,1024)
    const int pair = r & 15;
    const int gq   = (r >> 4) & 3;
    const int b    = x * 16 + (r >> 6);
    const int di    = pair >> 1;
    const int diffi = pair & 1;
    const int D     = 1 << di;
    const int Lout  = CL - diffi;
    const float* __restrict__ Xb = X + (size_t)b * (CC * CL);

    for (int i = tid; i < HALO; i += 256) inp[i] = 0.f;
    for (int i = HALO + CL + tid; i < BUF; i += 256) inp[i] = 0.f;

    #pragma unroll 1
    for (int gi = 0; gi < 8; ++gi) {
        const int g = gq * 8 + gi;
        // ---- stage summed (and optionally diffed) row for this group ----
        const int* __restrict__ Ig = I + (pair * CG + g) * CNCP;
        const int ch0 = Ig[0], ch1 = Ig[1], ch2 = Ig[2],
                  ch3 = Ig[3], ch4 = Ig[4], ch5 = Ig[5];
        const float* r0 = Xb + ch0 * CL; const float* r1 = Xb + ch1 * CL;
        const float* r2 = Xb + ch2 * CL; const float* r3 = Xb + ch3 * CL;
        const float* r4 = Xb + ch4 * CL; const float* r5 = Xb + ch5 * CL;

        #pragma unroll
        for (int cc = 0; cc < 2; ++cc) {
            const int pos = cc * 1024 + tid * 4;
            const float4 x0 = ld4(r0 + pos), x1 = ld4(r1 + pos), x2 = ld4(r2 + pos),
                         x3 = ld4(r3 + pos), x4 = ld4(r4 + pos), x5 = ld4(r5 + pos);
            float4 s;
            s.x = ((x0.x + x1.x) + (x2.x + x3.x)) + (x4.x + x5.x);
            s.y = ((x0.y + x1.y) + (x2.y + x3.y)) + (x4.y + x5.y);
            s.z = ((x0.z + x1.z) + (x2.z + x3.z)) + (x4.z + x5.z);
            s.w = ((x0.w + x1.w) + (x2.w + x3.w)) + (x4.w + x5.w);
            if (!diffi) {
                *(float4*)&inp[HALO + pos] = s;
            } else {
                float s4;
                if (pos + 4 < CL)
                    s4 = ((r0[pos + 4] + r1[pos + 4]) + (r2[pos + 4] + r3[pos + 4]))
                         + (r4[pos + 4] + r5[pos + 4]);
                else
                    s4 = s.w; // => diff 0 at padding position 2047
                const float4 d = make_float4(s.y - s.x, s.z - s.y, s.w - s.z, s4 - s.w);
                *(float4*)&inp[HALO + pos] = d;
            }
        }
        __syncthreads();

        // ---- conv + packed-index select + register bins, 2 pos/thread ----
        const float* __restrict__ Wg = Wt + (pair * CG + g) * 72;
        v2f bm0 = {0,0}, bm1 = {0,0}, bm2 = {0,0}, bm3 = {0,0},
            bm4 = {0,0}, bm5 = {0,0}, bm6 = {0,0}, bm7 = {0,0};
        unsigned bnpack = 0; // 8 nibble counters, <=8 each per g per thread

        #pragma unroll 1
        for (int p = 0; p < 4; ++p) {
            const int l = p * 512 + tid * 2;          // even; positions l, l+1
            v2f a0 = {0,0}, a1 = {0,0}, a2 = {0,0}, a3 = {0,0},
                a4 = {0,0}, a5 = {0,0}, a6 = {0,0}, a7 = {0,0};

            #define FK2(J, TV) { const float* wj = Wg + (J) * 8; \
                a0 = __builtin_elementwise_fma((v2f){wj[0], wj[0]}, TV, a0); \
                a1 = __builtin_elementwise_fma((v2f){wj[1], wj[1]}, TV, a1); \
                a2 = __builtin_elementwise_fma((v2f){wj[2], wj[2]}, TV, a2); \
                a3 = __builtin_elementwise_fma((v2f){wj[3], wj[3]}, TV, a3); \
                a4 = __builtin_elementwise_fma((v2f){wj[4], wj[4]}, TV, a4); \
                a5 = __builtin_elementwise_fma((v2f){wj[5], wj[5]}, TV, a5); \
                a6 = __builtin_elementwise_fma((v2f){wj[6], wj[6]}, TV, a6); \
                a7 = __builtin_elementwise_fma((v2f){wj[7], wj[7]}, TV, a7); }

            if (di == 0) {
                const float* base = &inp[HALO + l - 4];
                const v2f W0 = *(const v2f*)(base + 0), W1 = *(const v2f*)(base + 2),
                          W2 = *(const v2f*)(base + 4), W3 = *(const v2f*)(base + 6),
                          W4 = *(const v2f*)(base + 8);
                FK2(0, W0)
                FK2(1, ((v2f){W0.y, W1.x}))
                FK2(2, W1)
                FK2(3, ((v2f){W1.y, W2.x}))
                FK2(4, W2)
                FK2(5, ((v2f){W2.y, W3.x}))
                FK2(6, W3)
                FK2(7, ((v2f){W3.y, W4.x}))
                FK2(8, W4)
            } else {
                const float* base = &inp[HALO + l - 4 * D];
                #pragma unroll
                for (int j = 0; j < 9; ++j) {
                    const v2f tv = *(const v2f*)(base + j * D);
                    FK2(j, tv)
                }
            }
            #undef FK2

            const v2f q0 = packidx(a0, 0), q1 = packidx(a1, 1),
                      q2 = packidx(a2, 2), q3 = packidx(a3, 3),
                      q4 = packidx(a4, 4), q5 = packidx(a5, 5),
                      q6 = packidx(a6, 6), q7 = packidx(a7, 7);
            const v2f mx2 = vmax(vmax(vmax(q0, q1), vmax(q2, q3)),
                                 vmax(vmax(q4, q5), vmax(q6, q7)));
            const v2f mn2 = vmin(vmin(vmin(q0, q1), vmin(q2, q3)),
                                 vmin(vmin(q4, q5), vmin(q6, q7)));

            int mi0 = lowbits(mx2.x), mi1 = lowbits(mx2.y);
            const int ni0 = lowbits(mn2.x), ni1 = lowbits(mn2.y);

            const bool v1ok = (l + 1) < Lout;
            if (!v1ok) mi1 = 8;

            #define BINK(K) bm##K += (v2f){ (mi0 == (K)) ? mx2.x : 0.f, \
                                            (mi1 == (K)) ? mx2.y : 0.f };
            BINK(0) BINK(1) BINK(2) BINK(3) BINK(4) BINK(5) BINK(6) BINK(7)
            #undef BINK
            bnpack += (1u << (ni0 * 4)) + (v1ok ? (1u << (ni1 * 4)) : 0u);
        }

        // ---- fold parities, unpack nibbles ----
        float f0 = bm0.x + bm0.y, f1 = bm1.x + bm1.y, f2 = bm2.x + bm2.y,
              f3 = bm3.x + bm3.y, f4 = bm4.x + bm4.y, f5 = bm5.x + bm5.y,
              f6 = bm6.x + bm6.y, f7 = bm7.x + bm7.y;
        float h0 = (float)((bnpack >>  0) & 15), h1 = (float)((bnpack >>  4) & 15),
              h2 = (float)((bnpack >>  8) & 15), h3 = (float)((bnpack >> 12) & 15),
              h4 = (float)((bnpack >> 16) & 15), h5 = (float)((bnpack >> 20) & 15),
              h6 = (float)((bnpack >> 24) & 15), h7 = (float)((bnpack >> 28) & 15);

        // ---- reduce-scatter over 64 lanes (R10-proven, 10 shuffles/set) ----
        const int lane = tid & 63;
        const bool l5 = (lane & 32) != 0, l4 = (lane & 16) != 0, l3 = (lane & 8) != 0;

        #define RSCAT(q, v0, v1, v2, v3, v4, v5, v6, v7)                          \
            float q;                                                              \
            {                                                                     \
                float k0 = l5 ? v4 : v0, s0 = l5 ? v0 : v4;                       \
                float k1 = l5 ? v5 : v1, s1 = l5 ? v1 : v5;                       \
                float k2 = l5 ? v6 : v2, s2 = l5 ? v2 : v6;                       \
                float k3 = l5 ? v7 : v3, s3 = l5 ? v3 : v7;                       \
                k0 += __shfl_xor(s0, 32); k1 += __shfl_xor(s1, 32);               \
                k2 += __shfl_xor(s2, 32); k3 += __shfl_xor(s3, 32);               \
                float m0 = l4 ? k2 : k0, t0 = l4 ? k0 : k2;                       \
                float m1 = l4 ? k3 : k1, t1 = l4 ? k1 : k3;                       \
                m0 += __shfl_xor(t0, 16); m1 += __shfl_xor(t1, 16);               \
                q = l3 ? m1 : m0; float u = l3 ? m0 : m1;                         \
                q += __shfl_xor(u, 8);                                            \
                q += __shfl_xor(q, 4); q += __shfl_xor(q, 2);                     \
                q += __shfl_xor(q, 1);                                            \
            }
        RSCAT(qf, f0, f1, f2, f3, f4, f5, f6, f7)
        RSCAT(qc, h0, h1, h2, h3, h4, h5, h6, h7)
        #undef RSCAT

        // lane holds totals for bin = 4*bit5 + 2*bit4 + bit3
        if ((lane & 7) == 0) {
            const int bin = (l5 ? 4 : 0) + (l4 ? 2 : 0) + (l3 ? 1 : 0);
            float* wh = wavehist + (tid >> 6) * 16;
            wh[bin]     = qf;
            wh[8 + bin] = qc;
        }
        __syncthreads();

        if (tid < 16) {
            const float s = wavehist[tid] + wavehist[16 + tid]
                          + wavehist[32 + tid] + wavehist[48 + tid];
            const int which = tid >> 3, k = tid & 7;
            out[(size_t)b * 8192 + ((pair * 2 + which) * CG + g) * CK + k] = s;
        }
    }
}

extern "C" void kernel_launch(void* const* d_in, const int* in_sizes, int n_in,
                              void* d_out, int out_size, void* d_ws, size_t ws_size,
                              hipStream_t stream)
{
    const float* X = (const float*)d_in[0];
    const float* W = (const float*)d_in[1];
    const int*   I = (const int*)d_in[2];
    float* out = (float*)d_out;
    float* Wt  = (float*)d_ws; // 36864 floats = 144 KiB scratch

    transposeW<<<dim3((36864 + 255) / 256), dim3(256), 0, stream>>>(W, Wt);
    // 128 b x 16 pair x 4 gq = 8192 blocks -> 4+ generations w/ backfill
    hydra_fused<<<dim3(CB * 16 * 4), dim3(256), 0, stream>>>(X, Wt, I, out);
}